// Round 1
// baseline (879.094 us; speedup 1.0000x reference)
//
#include <hip/hip_runtime.h>
#include <hip/hip_bf16.h>

typedef __attribute__((ext_vector_type(4))) float f32x4;
typedef __attribute__((ext_vector_type(8))) short s16x8;
typedef __attribute__((ext_vector_type(4))) unsigned short u16x4;
typedef __attribute__((ext_vector_type(8))) unsigned short u16x8;

constexpr int B_ = 4, L_ = 4096, K_ = 48, D_ = 128;
constexpr int ROWS_PER_BLOCK = 2;             // nodes per block
constexpr int M_ = ROWS_PER_BLOCK * K_;       // 96 edge-rows
constexpr int THREADS1 = 512;                 // 8 waves

// RNE float -> bf16 (finite inputs)
__device__ __forceinline__ unsigned short f2bf(float f) {
    union { float f; unsigned u; } uf; uf.f = f;
    unsigned u = uf.u;
    return (unsigned short)((u + 0x7FFFu + ((u >> 16) & 1u)) >> 16);
}

// tanh-approx GELU (error ~1e-3, far below bf16 rounding noise)
__device__ __forceinline__ float gelu_f(float x) {
    float u = 0.7978845608028654f * x * (1.0f + 0.044715f * x * x);
    float e = __expf(2.0f * u);
    float t = 1.0f - 2.0f / (e + 1.0f);   // tanh(u); inf-safe
    return 0.5f * x * (1.0f + t);
}

// ---------------- kernel 0: weight prep (transpose + bf16) + zero accum ----
__global__ void prep_kernel(const float* __restrict__ fW1,
                            const float* __restrict__ fW2,
                            unsigned short* __restrict__ wsW1,
                            unsigned short* __restrict__ wsW2,
                            float* __restrict__ dGsum) {
    int t = blockIdx.x * blockDim.x + threadIdx.x;   // 64*256 = 16384
    int n = t >> 7, k = t & 127;
    wsW1[t] = f2bf(fW1[k * 128 + n]);                // wsW[n][k] = fW[k][n]
    wsW2[t] = f2bf(fW2[k * 128 + n]);
    if (t < 4) dGsum[t] = 0.0f;
}

// ---------------- kernel 1: fused filter-net + gather + conv-reduce --------
__global__ __launch_bounds__(THREADS1, 4) void filter_conv_kernel(
    const float* __restrict__ hV, const float* __restrict__ hE,
    const int* __restrict__ Eidx,
    const unsigned short* __restrict__ wsW1,
    const unsigned short* __restrict__ wsW2,
    const float* __restrict__ fb1, const float* __restrict__ fb2,
    float* __restrict__ xconv) {
    // sE: 96x128 bf16, row = edge, col = feature/k-dim; 256B rows, XOR-swizzled
    // (reused as T between the two matmuls). sW: 128x128 bf16 W^T [n][k].
    __shared__ __align__(16) unsigned short sE[M_ * D_];
    __shared__ __align__(16) unsigned short sW[D_ * D_];

    const int tid  = threadIdx.x;
    const int lane = tid & 63;
    const int wave = tid >> 6;
    const int g    = lane >> 4;     // k-group 0..3
    const int ln   = lane & 15;

    const int g0 = blockIdx.x * ROWS_PER_BLOCK;   // global node row
    const int b  = g0 >> 12;                      // / L_
    const float* hE_blk = hE + (size_t)g0 * (K_ * D_);
    const float* hV_b   = hV + (size_t)b * L_ * D_;

    // ---- stage W1 (already bf16 [n][k] in ws) into sW, swizzled ----
    {
        const u16x8* src = (const u16x8*)wsW1;
        #pragma unroll
        for (int j = 0; j < 4; ++j) {
            int c = tid + j * THREADS1;           // 16B chunk id, 2048 total
            int n = c >> 4, kc = c & 15;
            ((u16x8*)sW)[n * 16 + (kc ^ (n & 7))] = src[c];
        }
    }
    // ---- stage h_E tile (fp32 -> bf16) into sE, swizzled ----
    {
        const f32x4* src = (const f32x4*)hE_blk;
        #pragma unroll
        for (int j = 0; j < 6; ++j) {
            int c = tid + j * THREADS1;           // float4 id, 3072 total
            f32x4 v = src[c];
            u16x4 p = { f2bf(v.x), f2bf(v.y), f2bf(v.z), f2bf(v.w) };
            int row = c >> 5;                     // 32 float4 per 128-col row
            int inb = (c * 8) & 255;              // byte offset within bf16 row
            *(u16x4*)((char*)sE + row * 256 + (inb ^ ((row & 7) << 4))) = p;
        }
    }
    __syncthreads();

    // wave -> tile mapping: iL = local node, 2 ntiles, all 3 mtiles of its node
    const int iL  = wave >> 2;
    const int nt0 = (wave & 3) * 2;

    f32x4 acc[3][2];
    #pragma unroll
    for (int mt = 0; mt < 3; ++mt)
        #pragma unroll
        for (int n = 0; n < 2; ++n)
            #pragma unroll
            for (int q = 0; q < 4; ++q) acc[mt][n][q] = 0.0f;

    // ---- matmul1: T = hE_tile @ W1 ----
    #pragma unroll
    for (int ks = 0; ks < 4; ++ks) {
        const int kb = ks * 64 + g * 16;          // k byte offset of frag
        s16x8 a[3], bb[2];
        #pragma unroll
        for (int mt = 0; mt < 3; ++mt) {
            int row = iL * 48 + mt * 16 + ln;
            a[mt] = *(const s16x8*)((const char*)sE + row * 256 + (kb ^ ((row & 7) << 4)));
        }
        #pragma unroll
        for (int n = 0; n < 2; ++n) {
            int nn = (nt0 + n) * 16 + ln;
            bb[n] = *(const s16x8*)((const char*)sW + nn * 256 + (kb ^ ((nn & 7) << 4)));
        }
        #pragma unroll
        for (int mt = 0; mt < 3; ++mt)
            #pragma unroll
            for (int n = 0; n < 2; ++n)
                acc[mt][n] = __builtin_amdgcn_mfma_f32_16x16x32_bf16(a[mt], bb[n], acc[mt][n], 0, 0, 0);
    }
    __syncthreads();   // all waves done reading sE (A) and sW (W1)

    // ---- stage W2 into sW (overlap with epilogue VALU) ----
    {
        const u16x8* src = (const u16x8*)wsW2;
        #pragma unroll
        for (int j = 0; j < 4; ++j) {
            int c = tid + j * THREADS1;
            int n = c >> 4, kc = c & 15;
            ((u16x8*)sW)[n * 16 + (kc ^ (n & 7))] = src[c];
        }
    }
    // ---- epilogue1: gelu(acc + fb1) -> bf16 into sE (as T), re-zero acc ----
    #pragma unroll
    for (int n = 0; n < 2; ++n) {
        const int col  = (nt0 + n) * 16 + ln;
        const float bias = fb1[col];
        #pragma unroll
        for (int mt = 0; mt < 3; ++mt) {
            #pragma unroll
            for (int j = 0; j < 4; ++j) {
                int row = iL * 48 + mt * 16 + g * 4 + j;   // C-layout row (m89)
                float v = gelu_f(acc[mt][n][j] + bias);
                *(unsigned short*)((char*)sE + row * 256 + ((col * 2) ^ ((row & 7) << 4))) = f2bf(v);
                acc[mt][n][j] = 0.0f;
            }
        }
    }
    __syncthreads();

    // ---- matmul2: W = T @ W2 ----
    #pragma unroll
    for (int ks = 0; ks < 4; ++ks) {
        const int kb = ks * 64 + g * 16;
        s16x8 a[3], bb[2];
        #pragma unroll
        for (int mt = 0; mt < 3; ++mt) {
            int row = iL * 48 + mt * 16 + ln;
            a[mt] = *(const s16x8*)((const char*)sE + row * 256 + (kb ^ ((row & 7) << 4)));
        }
        #pragma unroll
        for (int n = 0; n < 2; ++n) {
            int nn = (nt0 + n) * 16 + ln;
            bb[n] = *(const s16x8*)((const char*)sW + nn * 256 + (kb ^ ((nn & 7) << 4)));
        }
        #pragma unroll
        for (int mt = 0; mt < 3; ++mt)
            #pragma unroll
            for (int n = 0; n < 2; ++n)
                acc[mt][n] = __builtin_amdgcn_mfma_f32_16x16x32_bf16(a[mt], bb[n], acc[mt][n], 0, 0, 0);
    }

    // ---- epilogue2: gelu(acc + fb2), gather x_j from h_V, reduce over k ----
    float xc[2] = {0.0f, 0.0f};
    const int gi = g0 + iL;
    const int* eidx = Eidx + (size_t)gi * K_;
    const float bias2_0 = fb2[nt0 * 16 + ln];
    const float bias2_1 = fb2[(nt0 + 1) * 16 + ln];
    #pragma unroll
    for (int mt = 0; mt < 3; ++mt) {
        #pragma unroll
        for (int j = 0; j < 4; ++j) {
            int k = mt * 16 + g * 4 + j;          // edge index within node
            int idx = eidx[k];
            const float* xrow = hV_b + (size_t)idx * D_;
            float w0 = gelu_f(acc[mt][0][j] + bias2_0);
            float w1 = gelu_f(acc[mt][1][j] + bias2_1);
            xc[0] += w0 * xrow[nt0 * 16 + ln];
            xc[1] += w1 * xrow[(nt0 + 1) * 16 + ln];
        }
    }
    // reduce across the 4 k-groups (lanes ^16, ^32)
    #pragma unroll
    for (int n = 0; n < 2; ++n) {
        xc[n] += __shfl_xor(xc[n], 16, 64);
        xc[n] += __shfl_xor(xc[n], 32, 64);
    }
    if (lane < 16) {
        xconv[(size_t)gi * D_ + nt0 * 16 + ln]       = xc[0];
        xconv[(size_t)gi * D_ + (nt0 + 1) * 16 + ln] = xc[1];
    }
}

// ---------------- kernel 2: mlp_head + masked per-batch accumulation -------
__global__ __launch_bounds__(256) void mlp_head_kernel(
    const float* __restrict__ xconv, const float* __restrict__ mask,
    const float* __restrict__ mW1, const float* __restrict__ mb1,
    const float* __restrict__ mW2, const float* __restrict__ mb2,
    const float* __restrict__ mW3, const float* __restrict__ mb3,
    float* __restrict__ dGsum) {
    constexpr int RPB = 16;
    __shared__ __align__(16) float sX[RPB][128];
    __shared__ float sH[RPB][128];
    const int tid = threadIdx.x, lane = tid & 63, wave = tid >> 6;
    const size_t row0 = (size_t)blockIdx.x * RPB;

    const f32x4* src = (const f32x4*)(xconv + row0 * 128);
    #pragma unroll
    for (int j = 0; j < 2; ++j) {
        int c = tid + j * 256;
        ((f32x4*)sX)[c] = src[c];
    }
    __syncthreads();

    // h1 = gelu(X @ mW1 + mb1); wave owns rows wave*4..+3; lane owns cols {lane, lane+64}
    float h[4][2];
    #pragma unroll
    for (int r = 0; r < 4; ++r) { h[r][0] = 0.0f; h[r][1] = 0.0f; }
    for (int d = 0; d < 128; ++d) {
        float w0 = mW1[d * 128 + lane];
        float w1 = mW1[d * 128 + lane + 64];
        #pragma unroll
        for (int r = 0; r < 4; ++r) {
            float x = sX[wave * 4 + r][d];
            h[r][0] += x * w0;
            h[r][1] += x * w1;
        }
    }
    float b0 = mb1[lane], b1 = mb1[lane + 64];
    #pragma unroll
    for (int r = 0; r < 4; ++r) {
        sH[wave * 4 + r][lane]      = gelu_f(h[r][0] + b0);
        sH[wave * 4 + r][lane + 64] = gelu_f(h[r][1] + b1);
    }
    __syncthreads();

    // h2 = gelu(H @ mW2 + mb2); lane owns col = lane (64 cols); then dG = h2 @ mW3 + mb3
    float h2[4] = {0.0f, 0.0f, 0.0f, 0.0f};
    for (int d = 0; d < 128; ++d) {
        float w = mW2[d * 64 + lane];
        #pragma unroll
        for (int r = 0; r < 4; ++r) h2[r] += sH[wave * 4 + r][d] * w;
    }
    const float bb = mb2[lane], w3 = mW3[lane], b3 = mb3[0];
    #pragma unroll
    for (int r = 0; r < 4; ++r) {
        float v = gelu_f(h2[r] + bb) * w3;
        #pragma unroll
        for (int s = 1; s < 64; s <<= 1) v += __shfl_xor(v, s, 64);
        if (lane == 0) {
            size_t row = row0 + wave * 4 + r;
            float dG = v + b3;
            atomicAdd(&dGsum[row >> 12], dG * mask[row]);
        }
    }
}

// ---------------- kernel 3: finalize out[b] = dGsum / sqrt(clip(len,1)) ----
__global__ void finalize_kernel(const float* __restrict__ mask,
                                const float* __restrict__ dGsum,
                                float* __restrict__ out) {
    const int b = blockIdx.x, tid = threadIdx.x;
    float s = 0.0f;
    for (int i = tid; i < L_; i += 256) s += mask[b * L_ + i];
    #pragma unroll
    for (int k = 1; k < 64; k <<= 1) s += __shfl_xor(s, k, 64);
    __shared__ float red[4];
    if ((tid & 63) == 0) red[tid >> 6] = s;
    __syncthreads();
    if (tid == 0) {
        float tot = red[0] + red[1] + red[2] + red[3];
        tot = fmaxf(tot, 1.0f);
        out[b] = dGsum[b] / sqrtf(tot);
    }
}

extern "C" void kernel_launch(void* const* d_in, const int* in_sizes, int n_in,
                              void* d_out, int out_size, void* d_ws, size_t ws_size,
                              hipStream_t stream) {
    const float* h_V  = (const float*)d_in[0];
    const float* h_E  = (const float*)d_in[1];
    const int*   E_idx = (const int*)d_in[2];
    const float* mask = (const float*)d_in[3];
    const float* fW1 = (const float*)d_in[4];
    const float* fb1 = (const float*)d_in[5];
    const float* fW2 = (const float*)d_in[6];
    const float* fb2 = (const float*)d_in[7];
    const float* mW1 = (const float*)d_in[8];
    const float* mb1 = (const float*)d_in[9];
    const float* mW2 = (const float*)d_in[10];
    const float* mb2 = (const float*)d_in[11];
    const float* mW3 = (const float*)d_in[12];
    const float* mb3 = (const float*)d_in[13];

    char* ws = (char*)d_ws;
    unsigned short* wsW1 = (unsigned short*)ws;              // 32 KB
    unsigned short* wsW2 = (unsigned short*)(ws + 32768);    // 32 KB
    float* xconv = (float*)(ws + 65536);                     // 16384*128*4 = 8 MB
    float* dGsum = (float*)(ws + 65536 + (size_t)B_ * L_ * D_ * 4);

    prep_kernel<<<64, 256, 0, stream>>>(fW1, fW2, wsW1, wsW2, dGsum);
    filter_conv_kernel<<<B_ * L_ / ROWS_PER_BLOCK, THREADS1, 0, stream>>>(
        h_V, h_E, E_idx, wsW1, wsW2, fb1, fb2, xconv);
    mlp_head_kernel<<<B_ * L_ / 16, 256, 0, stream>>>(
        xconv, mask, mW1, mb1, mW2, mb2, mW3, mb3, dGsum);
    finalize_kernel<<<B_, 256, 0, stream>>>(mask, dGsum, (float*)d_out);
}